// Round 1
// baseline (177.150 us; speedup 1.0000x reference)
//
#include <hip/hip_runtime.h>
#include <hip/hip_fp16.h>
#include <stdint.h>

#define NROWS 8192   // B*S
#define HDIM  128
#define KSUB  8
#define NC    4096
#define DSUB  16
#define OUTD  6

// fallback margin: split-fp16 bound ~1.5e-5 + C-init accumulation-order
// rounding ~1.5e-5 worst case -> keep the original 4x margin => 1.2e-4
#define FB_TAU 1.2e-4f
#define DOTSCALE (-2.0f / 4096.0f)  // exact pow2: s = DOTSCALE * q
#define QSCALE   (-2048.0f)         // 1/DOTSCALE, exact pow2: Cinit = QSCALE*nrm

typedef _Float16 f16x8 __attribute__((ext_vector_type(8)));
typedef float    f32x4 __attribute__((ext_vector_type(4)));

// ws layout (bytes): total 8,519,680
#define XK_OFF 0u            // xk:   [KSUB][NROWS][DSUB] fp32, 4 MiB
#define CN_OFF 4194304u      // cnorm:[KSUB][NC] fp32, 128 KiB
#define B1_OFF 4325376u      // B1S:  [KSUB][256 tiles][64 lanes] f16x8, 2 MiB
#define PK_OFF 6422528u      // pk:   [4 splits][NROWS][KSUB] u64, 2 MiB

// ---------------- Kernel 1: prep = MLP + cnorm + bprep (512 blocks, 16 rows each) ------
__global__ __launch_bounds__(256) void prep_kernel(
    const float* __restrict__ z, const float* __restrict__ W1, const float* __restrict__ b1,
    const float* __restrict__ W2, const float* __restrict__ b2,
    const float* __restrict__ ce,
    float* __restrict__ xk, float* __restrict__ cnorm, f16x8* __restrict__ B1S)
{
    __shared__ float h1s[16 * HDIM];    // 8 KiB
    __shared__ float w2s[HDIM * HDIM];  // 64 KiB
    const int t = threadIdx.x;
    const int row0 = blockIdx.x * 16;

    // ---- bprep: one 16x16-tile fragment per thread (512 x 256 = 131072 entries) ----
    // entry e = (k, tile, lane); quad<2 -> hi, quad>=2 -> lo (B2 = B1[lane^32]).
    {
        const int e = blockIdx.x * 256 + t;
        const int k    = e >> 14;
        const int tile = (e >> 6) & 255;
        const int lane = e & 63;
        const int col  = lane & 15;
        const int quad = lane >> 4;
        const int dims = (quad & 1) * 8;
        const int part = quad >> 1;                      // 0: hi half of K, 1: lo half
        const int n = tile * 16 + col;
        const float* cp = &ce[((size_t)k * NC + n) * DSUB + dims];
        f16x8 hi, lo;
        #pragma unroll
        for (int j = 0; j < 8; ++j) {
            const float s = cp[j] * 16.0f;               // pow2 scale keeps lo normal
            const _Float16 h = (_Float16)s;
            hi[j] = h;
            lo[j] = (_Float16)(s - (float)h);
        }
        B1S[e] = part ? lo : hi;
    }

    // centroid norms (first 128 blocks cover KSUB*NC = 32768 centroids)
    if (blockIdx.x < (KSUB * NC) / 256) {
        const int g = blockIdx.x * 256 + t;
        const float4* cp = (const float4*)&ce[(size_t)g * DSUB];
        float nn = 0.f;
        #pragma unroll
        for (int q = 0; q < 4; ++q) {
            const float4 v = cp[q];
            nn = fmaf(v.x, v.x, nn); nn = fmaf(v.y, v.y, nn);
            nn = fmaf(v.z, v.z, nn); nn = fmaf(v.w, v.w, nn);
        }
        cnorm[g] = nn;
    }

    // stage W2 (coalesced)
    {
        const float4* g4 = (const float4*)W2;
        float4* s4 = (float4*)w2s;
        #pragma unroll
        for (int q = 0; q < 16; ++q) s4[t + q * 256] = g4[t + q * 256];
    }

    // phase A: h1 = relu(z @ W1 + b1) into LDS (16x128)
    #pragma unroll
    for (int e = 0; e < 8; ++e) {
        const int idx = e * 256 + t;
        const int r = idx >> 7, j = idx & 127;
        const int n = row0 + r;
        float acc = b1[j];
        acc = fmaf(z[n * 3 + 0], W1[0 * HDIM + j], acc);
        acc = fmaf(z[n * 3 + 1], W1[1 * HDIM + j], acc);
        acc = fmaf(z[n * 3 + 2], W1[2 * HDIM + j], acc);
        h1s[idx] = fmaxf(acc, 0.f);
    }
    __syncthreads();

    // phase B: 2 rows x 4 cols per thread (same per-output fma chain as before)
    const int c4 = (t & 31) * 4;
    const int r2 = (t >> 5) * 2;
    float acc[2][4];
    #pragma unroll
    for (int a = 0; a < 2; ++a)
        #pragma unroll
        for (int b = 0; b < 4; ++b) acc[a][b] = 0.f;

    for (int k4 = 0; k4 < HDIM; k4 += 4) {
        float hh[2][4], ww[4][4];
        #pragma unroll
        for (int q = 0; q < 2; ++q) {
            const float4 v = *(const float4*)&h1s[(r2 + q) * HDIM + k4];
            hh[q][0] = v.x; hh[q][1] = v.y; hh[q][2] = v.z; hh[q][3] = v.w;
        }
        #pragma unroll
        for (int p = 0; p < 4; ++p) {
            const float4 v = *(const float4*)&w2s[(k4 + p) * HDIM + c4];
            ww[p][0] = v.x; ww[p][1] = v.y; ww[p][2] = v.z; ww[p][3] = v.w;
        }
        #pragma unroll
        for (int q = 0; q < 2; ++q)
            #pragma unroll
            for (int p = 0; p < 4; ++p) {
                acc[q][0] = fmaf(hh[q][p], ww[p][0], acc[q][0]);
                acc[q][1] = fmaf(hh[q][p], ww[p][1], acc[q][1]);
                acc[q][2] = fmaf(hh[q][p], ww[p][2], acc[q][2]);
                acc[q][3] = fmaf(hh[q][p], ww[p][3], acc[q][3]);
            }
    }

    const float4 bb = *(const float4*)&b2[c4];
    const int kk = c4 >> 4;
    const int dd = c4 & 15;
    #pragma unroll
    for (int q = 0; q < 2; ++q) {
        float4 o;
        o.x = fmaxf(acc[q][0] + bb.x, 0.f);
        o.y = fmaxf(acc[q][1] + bb.y, 0.f);
        o.z = fmaxf(acc[q][2] + bb.z, 0.f);
        o.w = fmaxf(acc[q][3] + bb.w, 0.f);
        *(float4*)&xk[((size_t)kk * NROWS + (row0 + r2 + q)) * DSUB + dd] = o;
    }
}

// ---------------- Kernel 2: barrier-free argmax over q = -2048*nrm + dot ---------------
// Restructure vs r9/r10: (1) B fragments read DIRECTLY from L2 (coalesced 16B/lane,
// b2 hits the same cache lines as b1) -- no LDS staging, ZERO __syncthreads in the
// main loop (old version drained 16 barrier/L2-latency cycles per block).
// (2) nrm folded into the MFMA C operand (Cinit = -2048*nrm; DOTSCALE exact pow2,
// so s = DOTSCALE*q exactly) -> per-value update is cmp+cndmask+med3+max (4 VALU),
// no fmaf. (3) 4 row-groups per wave (64 rows): 2 B-loads + 1 cnorm read amortize
// over 16 values. grid (32,8,4) = 1024 blocks = exactly 4 blocks/CU (the residency
// observed in r10) -> single generation. LDS 4 KiB. Target VGPR ~110 (cap 128).
__global__ __launch_bounds__(256, 4) void argmin_kernel(
    const float* __restrict__ xk, const f16x8* __restrict__ B1S,
    const float* __restrict__ cnorm, unsigned long long* __restrict__ pk)
{
    __shared__ float cnL[1024];     // 4 KiB: QSCALE * cnorm for this (k, cz)
    const int t = threadIdx.x;
    const int lane = t & 63;
    const int wid  = t >> 6;
    const int k  = blockIdx.y;                 // 0..7
    const int cz = blockIdx.z;                 // 0..3
    const int col  = lane & 15;
    const int quad = lane >> 4;
    const int dims = (quad & 1) * 8;
    const int part = quad >> 1;
    const int lane2 = lane ^ 32;               // hi/lo-split partner lane
    const int rowbase = (blockIdx.x * 4 + wid) * 64;

    // stage scaled norms once (the only barrier in this kernel)
    {
        const float* cnp0 = &cnorm[k * NC + cz * 1024];
        #pragma unroll
        for (int q = 0; q < 4; ++q) cnL[t + q * 256] = cnp0[t + q * 256] * QSCALE;
    }

    // A fragments for 4 groups of 16 rows (hi/lo split, exact)
    f16x8 A[4];
    #pragma unroll
    for (int g = 0; g < 4; ++g) {
        const int row = rowbase + g * 16 + col;
        const float* xp = &xk[((size_t)k * NROWS + row) * DSUB + dims];
        f16x8 hi, lo;
        #pragma unroll
        for (int j = 0; j < 8; ++j) {
            const float s = xp[j] * 256.0f;
            const _Float16 h = (_Float16)s;
            hi[j] = h;
            lo[j] = (_Float16)(s - (float)h);
        }
        A[g] = part ? lo : hi;
    }

    float m1[4][4], m2[4][4];   // running max / second-max of q (argmax == argmin of s)
    int   idx[4][4];
    #pragma unroll
    for (int g = 0; g < 4; ++g)
        #pragma unroll
        for (int j = 0; j < 4; ++j) { m1[g][j] = -1e30f; m2[g][j] = -1e30f; idx[g][j] = 0; }

    const f16x8* gp = &B1S[((size_t)k * 256 + cz * 64) * 64];

    // prefetch tile 0
    f16x8 b1 = gp[lane];
    f16x8 b2 = gp[lane2];

    __syncthreads();            // cnL ready

    for (int t64 = 0; t64 < 64; ++t64) {
        // prefetch next tile (wraps to 0 on last iter; harmless discard)
        const int nt = (t64 + 1) & 63;
        f16x8 nb1 = gp[nt * 64 + lane];
        f16x8 nb2 = gp[nt * 64 + lane2];

        const float nrm = cnL[t64 * 16 + col];         // already QSCALE-scaled
        const f32x4 ci = {nrm, nrm, nrm, nrm};
        const int c = ((cz * 64 + t64) << 4) + col;

        #pragma unroll
        for (int g = 0; g < 4; ++g) {
            f32x4 p = __builtin_amdgcn_mfma_f32_16x16x32_f16(A[g], b1, ci, 0, 0, 0);
            p       = __builtin_amdgcn_mfma_f32_16x16x32_f16(A[g], b2, p, 0, 0, 0);
            #pragma unroll
            for (int j = 0; j < 4; ++j) {
                const float q = p[j];
                const bool gt = q > m1[g][j];
                m2[g][j] = __builtin_amdgcn_fmed3f(q, m1[g][j], m2[g][j]);
                idx[g][j] = gt ? c : idx[g][j];
                m1[g][j] = fmaxf(q, m1[g][j]);
            }
        }
        b1 = nb1;
        b2 = nb2;
    }

    // reduce across the 16 lanes of each quad (argmax domain)
    #pragma unroll
    for (int off = 1; off < 16; off <<= 1) {
        #pragma unroll
        for (int g = 0; g < 4; ++g)
            #pragma unroll
            for (int j = 0; j < 4; ++j) {
                const float om1 = __shfl_xor(m1[g][j], off, 64);
                const float om2 = __shfl_xor(m2[g][j], off, 64);
                const int  oidx = __shfl_xor(idx[g][j], off, 64);
                const bool better = (om1 > m1[g][j]) ||
                                    (om1 == m1[g][j] && oidx < idx[g][j]);
                m2[g][j] = fmaxf(fminf(m1[g][j], om1), fmaxf(m2[g][j], om2));
                m1[g][j] = better ? om1 : m1[g][j];
                idx[g][j] = better ? oidx : idx[g][j];
            }
    }

    if (col == 0) {
        #pragma unroll
        for (int g = 0; g < 4; ++g)
            #pragma unroll
            for (int j = 0; j < 4; ++j) {
                const int row = rowbase + g * 16 + quad * 4 + j;
                const float s1 = m1[g][j] * DOTSCALE;              // exact pow2 scale
                const float dl = (m1[g][j] - m2[g][j]) * (2.0f / 4096.0f);  // s2-s1 >= 0
                unsigned u = __float_as_uint(s1);
                u = (u & 0x80000000u) ? ~u : (u | 0x80000000u);    // order-preserving
                const unsigned short dh = __half_as_ushort(__float2half(dl));
                pk[((size_t)cz * NROWS + row) * KSUB + k] =
                    ((unsigned long long)u << 32) |
                    ((unsigned)dh << 16) | (unsigned)idx[g][j];
            }
    }
}

// ---------------- Kernel 3: finish = merge 4 splits + exact rescue + LUT output --------
__global__ __launch_bounds__(256) void finish_kernel(
    const float* __restrict__ xk, const float* __restrict__ ce,
    const float* __restrict__ cnorm, const unsigned long long* __restrict__ pk,
    const float* __restrict__ W3, const float* __restrict__ b3,
    float* __restrict__ out)
{
    __shared__ int codes_s[256];
    __shared__ int wl_s[256];
    __shared__ int wcnt;
    const int t = threadIdx.x;
    const int row0 = blockIdx.x * 32;
    if (t == 0) wcnt = 0;
    __syncthreads();

    // merge 4 splits for (row, k) = (row0 + t>>3, t&7)
    {
        const int row = row0 + (t >> 3);
        const int k = t & 7;
        unsigned long long p[4];
        #pragma unroll
        for (int s = 0; s < 4; ++s)
            p[s] = pk[((size_t)s * NROWS + row) * KSUB + k];
        unsigned long long w = p[0];
        #pragma unroll
        for (int s = 1; s < 4; ++s) w = p[s] < w ? p[s] : w;
        const unsigned uw = (unsigned)(w >> 32);
        const float m1w = __uint_as_float((uw & 0x80000000u) ? (uw ^ 0x80000000u) : ~uw);
        float m2g = m1w + (float)__ushort_as_half((unsigned short)((unsigned)w >> 16));
        #pragma unroll
        for (int s = 0; s < 4; ++s) {
            if (p[s] != w) {   // splits have disjoint idx ranges -> pk values unique
                const unsigned us = (unsigned)(p[s] >> 32);
                m2g = fminf(m2g, __uint_as_float(
                    (us & 0x80000000u) ? (us ^ 0x80000000u) : ~us));
            }
        }
        codes_s[t] = (int)(w & 0xFFFFull);
        if (m2g - m1w < FB_TAU) {      // near-tie: exact fp32 rescan needed
            const int slot = atomicAdd(&wcnt, 1);
            wl_s[slot] = t;
        }
    }
    __syncthreads();

    // exact fp32 rescue, wave-per-item over the block-local worklist
    {
        const int lane = t & 63;
        const int wid = t >> 6;
        const int nitems = wcnt;
        for (int i = wid; i < nitems; i += 4) {
            const int wg = wl_s[i];
            const int row = row0 + (wg >> 3), k = wg & 7;
            float xr[DSUB];
            {
                const float* xp = &xk[((size_t)k * NROWS + row) * DSUB];
                #pragma unroll
                for (int q = 0; q < DSUB; q += 4) {
                    const float4 v = *(const float4*)&xp[q];
                    xr[q + 0] = -2.f * v.x; xr[q + 1] = -2.f * v.y;
                    xr[q + 2] = -2.f * v.z; xr[q + 3] = -2.f * v.w;
                }
            }
            float bm = 1e30f; int bi = NC;
            for (int c = lane; c < NC; c += 64) {
                const float* cp = &ce[((size_t)k * NC + c) * DSUB];
                float s = cnorm[k * NC + c];
                #pragma unroll
                for (int d = 0; d < DSUB; ++d) s = fmaf(xr[d], cp[d], s);
                if (s < bm) { bm = s; bi = c; }
            }
            #pragma unroll
            for (int off = 1; off < 64; off <<= 1) {
                const float om = __shfl_xor(bm, off, 64);
                const int  oi = __shfl_xor(bi, off, 64);
                const bool better = (om < bm) || (om == bm && oi < bi);
                bm = better ? om : bm;
                bi = better ? oi : bi;
            }
            if (lane == 0) codes_s[wg] = bi;
        }
    }
    __syncthreads();

    // output: 32 rows x 6 = 192 outputs
    if (t < 32 * OUTD) {
        const int nl = t / OUTD;
        const int o = t - nl * OUTD;
        const int n = row0 + nl;
        float acc = b3[o];
        #pragma unroll
        for (int k = 0; k < KSUB; ++k) {
            const int code = codes_s[nl * KSUB + k];
            const float* cp = &ce[((size_t)k * NC + code) * DSUB];
            const float* wp = &W3[(k * DSUB) * OUTD + o];
            #pragma unroll
            for (int d = 0; d < DSUB; ++d)
                acc = fmaf(cp[d], wp[d * OUTD], acc);
        }
        out[n * OUTD + o] = acc;
    }
}

extern "C" void kernel_launch(void* const* d_in, const int* in_sizes, int n_in,
                              void* d_out, int out_size, void* d_ws, size_t ws_size,
                              hipStream_t stream)
{
    const float* z  = (const float*)d_in[0];
    const float* W1 = (const float*)d_in[1];
    const float* b1 = (const float*)d_in[2];
    const float* W2 = (const float*)d_in[3];
    const float* b2 = (const float*)d_in[4];
    const float* ce = (const float*)d_in[5];
    const float* W3 = (const float*)d_in[6];
    const float* b3 = (const float*)d_in[7];

    char* ws = (char*)d_ws;
    float* xk    = (float*)(ws + XK_OFF);
    float* cnorm = (float*)(ws + CN_OFF);
    f16x8* B1S   = (f16x8*)(ws + B1_OFF);
    unsigned long long* pk = (unsigned long long*)(ws + PK_OFF);

    hipLaunchKernelGGL(prep_kernel, dim3(512), dim3(256), 0, stream,
                       z, W1, b1, W2, b2, ce, xk, cnorm, B1S);
    hipLaunchKernelGGL(argmin_kernel, dim3(32, 8, 4), dim3(256), 0, stream,
                       xk, B1S, cnorm, pk);
    hipLaunchKernelGGL(finish_kernel, dim3(256), dim3(256), 0, stream,
                       xk, ce, cnorm, pk, W3, b3, (float*)d_out);
}